// Round 1
// baseline (376.846 us; speedup 1.0000x reference)
//
#include <hip/hip_runtime.h>
#include <hip/hip_bf16.h>

// ChamferLoss: x,y (16,4096,3) f32 -> scalar
// dist[b,i,j] = sqrt(eps + max(||y_i||^2 + ||x_j||^2 - 2 y_i.x_j, 0))
// out = mean_j min_i dist + mean_i min_j dist
//
// sqrt is monotone -> min over squared form, sqrt once per query point.
// Per pair inner op: term = d2 + (-2q).d  (3 fma) ; min (1 op).
// minsq = q2 + min_i term  (q2 loop-invariant, folded out of inner loop).

#define NP 4096
#define NB 16
#define BLK 128
#define RQ 4           // queries per thread
#define QCHUNK (NP / (BLK * RQ))   // 8

__global__ void chamfer_zero(float* out) { out[0] = 0.0f; }

__global__ __launch_bounds__(BLK) void chamfer_main(
    const float* __restrict__ x, const float* __restrict__ y,
    float* __restrict__ out) {
  const int zz  = blockIdx.y;       // dir*16 + batch
  const int dir = zz >> 4;
  const int b   = zz & 15;

  const float* q_base  = (dir == 0 ? x : y) + (size_t)b * NP * 3;
  const float* d_base  = (dir == 0 ? y : x) + (size_t)b * NP * 3;

  // each thread owns RQ query points, strided by BLK for coalescing
  float qpx[RQ], qpy[RQ], qpz[RQ], q2[RQ], m[RQ];
#pragma unroll
  for (int r = 0; r < RQ; ++r) {
    const int qi = blockIdx.x * (BLK * RQ) + r * BLK + threadIdx.x;
    const float qx = q_base[qi * 3 + 0];
    const float qy = q_base[qi * 3 + 1];
    const float qz = q_base[qi * 3 + 2];
    q2[r]  = qx * qx + qy * qy + qz * qz;
    qpx[r] = -2.0f * qx;
    qpy[r] = -2.0f * qy;
    qpz[r] = -2.0f * qz;
    m[r]   = 3.4e38f;
  }

  // loop over full database; i is block-uniform -> scalar loads expected
#pragma unroll 4
  for (int i = 0; i < NP; ++i) {
    const float dx = d_base[i * 3 + 0];
    const float dy = d_base[i * 3 + 1];
    const float dz = d_base[i * 3 + 2];
    const float d2 = dx * dx + dy * dy + dz * dz;
#pragma unroll
    for (int r = 0; r < RQ; ++r) {
      const float t = fmaf(dx, qpx[r], fmaf(dy, qpy[r], fmaf(dz, qpz[r], d2)));
      m[r] = fminf(m[r], t);
    }
  }

  // epilogue: dist and partial mean
  float local = 0.0f;
#pragma unroll
  for (int r = 0; r < RQ; ++r) {
    const float sq = fmaxf(q2[r] + m[r], 0.0f);
    local += sqrtf(sq + 1e-6f);
  }
  local *= (1.0f / (float)(NB * NP));   // both directions share denominator

  // wave (64) reduction
#pragma unroll
  for (int off = 32; off > 0; off >>= 1)
    local += __shfl_down(local, off);

  __shared__ float warp_sums[BLK / 64];
  const int lane = threadIdx.x & 63;
  const int wid  = threadIdx.x >> 6;
  if (lane == 0) warp_sums[wid] = local;
  __syncthreads();
  if (threadIdx.x == 0) {
    float s = 0.0f;
#pragma unroll
    for (int w = 0; w < BLK / 64; ++w) s += warp_sums[w];
    atomicAdd(out, s);
  }
}

extern "C" void kernel_launch(void* const* d_in, const int* in_sizes, int n_in,
                              void* d_out, int out_size, void* d_ws, size_t ws_size,
                              hipStream_t stream) {
  const float* x = (const float*)d_in[0];
  const float* y = (const float*)d_in[1];
  float* out = (float*)d_out;

  chamfer_zero<<<1, 1, 0, stream>>>(out);
  dim3 grid(QCHUNK, 2 * NB);   // 8 x 32 = 256 blocks
  chamfer_main<<<grid, BLK, 0, stream>>>(x, y, out);
}

// Round 2
// 105.011 us; speedup vs baseline: 3.5886x; 3.5886x over previous
//
#include <hip/hip_runtime.h>
#include <hip/hip_bf16.h>

// ChamferLoss: x,y (16,4096,3) f32 -> scalar.
// R2: split db dim into SEG segments for occupancy (R1: 5.6% occ, 17% VALUBusy,
// half the SIMDs idle). Partial mins combined via atomicMin on order-preserving
// uint encoding. db segment staged in LDS as float4(dx,dy,dz,d2) -> inner loop
// is exactly 3 fma + 1 min per pair, uniform ds_read_b128 broadcast.

#define NP 4096
#define NB 16
#define BLK 256
#define RQ 4                       // queries per thread
#define QCHUNK (NP / (BLK * RQ))   // 4
#define SEG 8
#define DCHUNK (NP / SEG)          // 512
#define NQ_TOTAL (2 * NB * NP)     // 131072 (dir,b,q) triples

__device__ __forceinline__ unsigned enc(float f) {
  unsigned u = __float_as_uint(f);
  return (u & 0x80000000u) ? ~u : (u | 0x80000000u);
}
__device__ __forceinline__ float dec(unsigned k) {
  unsigned u = (k & 0x80000000u) ? (k ^ 0x80000000u) : ~k;
  return __uint_as_float(u);
}

__global__ __launch_bounds__(BLK) void chamfer_main(
    const float* __restrict__ x, const float* __restrict__ y,
    unsigned* __restrict__ minkey) {
  const int zz  = blockIdx.y;       // dir*16 + batch
  const int dir = zz >> 4;
  const int b   = zz & 15;
  const int seg = blockIdx.z;

  const float* q_base = (dir == 0 ? x : y) + (size_t)b * NP * 3;
  const float* d_base = (dir == 0 ? y : x) + (size_t)b * NP * 3;

  // stage db segment into LDS as (dx,dy,dz,d2)
  __shared__ float4 dpt[DCHUNK];
  for (int t = threadIdx.x; t < DCHUNK; t += BLK) {
    const int i = seg * DCHUNK + t;
    const float dx = d_base[i * 3 + 0];
    const float dy = d_base[i * 3 + 1];
    const float dz = d_base[i * 3 + 2];
    dpt[t] = make_float4(dx, dy, dz, dx * dx + dy * dy + dz * dz);
  }
  __syncthreads();

  float qpx[RQ], qpy[RQ], qpz[RQ], m[RQ];
#pragma unroll
  for (int r = 0; r < RQ; ++r) {
    const int qi = blockIdx.x * (BLK * RQ) + r * BLK + threadIdx.x;
    qpx[r] = -2.0f * q_base[qi * 3 + 0];
    qpy[r] = -2.0f * q_base[qi * 3 + 1];
    qpz[r] = -2.0f * q_base[qi * 3 + 2];
    m[r]   = 3.4e38f;
  }

#pragma unroll 4
  for (int t = 0; t < DCHUNK; ++t) {
    const float4 d = dpt[t];        // uniform address -> LDS broadcast
#pragma unroll
    for (int r = 0; r < RQ; ++r) {
      const float v = fmaf(d.x, qpx[r], fmaf(d.y, qpy[r], fmaf(d.z, qpz[r], d.w)));
      m[r] = fminf(m[r], v);
    }
  }

#pragma unroll
  for (int r = 0; r < RQ; ++r) {
    const int qi = blockIdx.x * (BLK * RQ) + r * BLK + threadIdx.x;
    atomicMin(&minkey[(size_t)zz * NP + qi], enc(m[r]));
  }
}

__global__ __launch_bounds__(BLK) void chamfer_finish(
    const float* __restrict__ x, const float* __restrict__ y,
    const unsigned* __restrict__ minkey, float* __restrict__ out) {
  const int g   = blockIdx.x * BLK + threadIdx.x;   // 0 .. NQ_TOTAL-1
  const int zz  = g >> 12;
  const int qi  = g & (NP - 1);
  const int dir = zz >> 4;
  const int b   = zz & 15;
  const float* q_base = (dir == 0 ? x : y) + (size_t)b * NP * 3;

  const float qx = q_base[qi * 3 + 0];
  const float qy = q_base[qi * 3 + 1];
  const float qz = q_base[qi * 3 + 2];
  const float q2 = qx * qx + qy * qy + qz * qz;
  const float m  = dec(minkey[g]);
  const float sq = fmaxf(q2 + m, 0.0f);
  float local = sqrtf(sq + 1e-6f) * (1.0f / (float)(NB * NP));

#pragma unroll
  for (int off = 32; off > 0; off >>= 1)
    local += __shfl_down(local, off);

  __shared__ float wsum[BLK / 64];
  if ((threadIdx.x & 63) == 0) wsum[threadIdx.x >> 6] = local;
  __syncthreads();
  if (threadIdx.x == 0) {
    float s = 0.0f;
#pragma unroll
    for (int w = 0; w < BLK / 64; ++w) s += wsum[w];
    atomicAdd(out, s);
  }
}

extern "C" void kernel_launch(void* const* d_in, const int* in_sizes, int n_in,
                              void* d_out, int out_size, void* d_ws, size_t ws_size,
                              hipStream_t stream) {
  const float* x = (const float*)d_in[0];
  const float* y = (const float*)d_in[1];
  float* out = (float*)d_out;
  unsigned* minkey = (unsigned*)d_ws;   // NQ_TOTAL uints = 512 KB

  hipMemsetAsync(minkey, 0xFF, NQ_TOTAL * sizeof(unsigned), stream);
  hipMemsetAsync(out, 0, sizeof(float), stream);

  dim3 grid(QCHUNK, 2 * NB, SEG);       // 4 x 32 x 8 = 1024 blocks
  chamfer_main<<<grid, BLK, 0, stream>>>(x, y, minkey);
  chamfer_finish<<<NQ_TOTAL / BLK, BLK, 0, stream>>>(x, y, minkey, out);
}